// Round 3
// baseline (388.676 us; speedup 1.0000x reference)
//
#include <hip/hip_runtime.h>
#include <math.h>

#define NN 50000
#define NE 800000
#define NG 64

// ---------------- sort pipeline geometry ----------------
#define CB    1024                        // edges per score/scatter block
#define NBLK  782                         // ceil(NE / CB)
#define NBUCK 196                         // ceil(NN / 256), bucket = dst >> 8

static_assert(NBLK * CB >= NE, "chunk cover");
static_assert((NBUCK - 1) == (NN - 1) / 256, "bucket count");

// ---------------- ws layout (float offsets) ----------------
#define WS_C     0                       // 8 floats: [h*4 + {att.Wl, att.Wr, att.We, att.B}]
#define WS_ACC   16                      // 4*NN floats: {den0,den1,t10,t11} per node (float4)
#define WS_BNSUM (WS_ACC + 4*NN)         // 128 (fallback path)
#define WS_BNSQ  (WS_BNSUM + 128)        // 128 (fallback path)
#define WS_MOM   WS_BNSUM                // dense path: 14 floats (overlaps BNSUM, paths exclusive)
#define WS_EX    (WS_BNSQ + 128)         // 257 u32 bucket exclusive offsets
#define WS_CNT   (WS_EX + 272)           // 256*NBLK u32, bucket-major [b][blk]
#define WS_REC0  (WS_CNT + 256*NBLK)     // NE float4 = {e0, e1, xs, asfloat(dst)}
#define WS_SORT  (WS_REC0 + 4*NE)        // NE float4, bucket-partitioned
#define WS_END   (WS_SORT + 4*NE)
#define WS_NEED_BYTES ((size_t)WS_END * 4 + 256)

static_assert(((WS_REC0 * 4) % 16) == 0, "rec0 16B alignment");
static_assert(((WS_SORT * 4) % 16) == 0, "sort 16B alignment");
static_assert(NE % 4 == 0, "edge unroll");

// ---------------- shared score machinery ----------------
#define STEP(wl_, wr_, we_, bb_, at_, xs_, xd_, ae_, acc_)                 \
  { float tt = fmaf(we_, ae_, bb_); tt = fmaf(wr_, xd_, tt);               \
    tt = fmaf(wl_, xs_, tt); acc_ = fmaf(fabsf(tt), at_, acc_); }

#define SMEM_WEIGHTS_DECL                                                  \
  __shared__ __align__(16) float sWl[256], sWr[256], sWe[256], sB[256], sAt[256];

#define SMEM_WEIGHTS_LOAD                                                  \
  { int t_ = threadIdx.x;                                                  \
    sWl[t_] = Wl[t_]; sWr[t_] = Wr[t_]; sWe[t_] = We[t_];                  \
    sB[t_] = bl[t_] + br[t_]; sAt[t_] = att[t_]; }                         \
  __syncthreads();

#define SCORES(xs_, xd_, ae_, accA, accB, out0, out1)                      \
  { float lin0 = fmaf(c0.x, xs_, fmaf(c0.y, xd_, fmaf(c0.z, ae_, c0.w))); \
    out0 = fmaf(0.4f, accA, 0.6f * lin0);                                  \
    float lin1 = fmaf(c1.x, xs_, fmaf(c1.y, xd_, fmaf(c1.z, ae_, c1.w))); \
    out1 = fmaf(0.4f, accB, 0.6f * lin1); }

// ---- 4-edge score core (dense k_score AND fallback k12f) ----
#define STEP4(c, q0, q1, q2, q3)                                           \
  STEP(wl.c, wr.c, we.c, bb.c, at.c, xs0, xd0, ae0, q0)                    \
  STEP(wl.c, wr.c, we.c, bb.c, at.c, xs1, xd1, ae1, q1)                    \
  STEP(wl.c, wr.c, we.c, bb.c, at.c, xs2, xd2, ae2, q2)                    \
  STEP(wl.c, wr.c, we.c, bb.c, at.c, xs3, xd3, ae3, q3)

#define SCORE_CORE                                                         \
  int4 s4 = *(const int4*)&ei[base];                                       \
  int4 dd4 = *(const int4*)&ei[NE + base];                                 \
  float4 ae4 = *(const float4*)&eattr[base];                               \
  float xs0 = x[s4.x], xs1 = x[s4.y], xs2 = x[s4.z], xs3 = x[s4.w];        \
  float xd0 = x[dd4.x], xd1 = x[dd4.y], xd2 = x[dd4.z], xd3 = x[dd4.w];    \
  float ae0 = ae4.x, ae1 = ae4.y, ae2 = ae4.z, ae3 = ae4.w;

#define SCORE_LOOPS                                                        \
  float a00 = 0.f, a01 = 0.f, a02 = 0.f, a03 = 0.f;                        \
  float a10 = 0.f, a11 = 0.f, a12 = 0.f, a13 = 0.f;                        \
  _Pragma("unroll 2")                                                      \
  for (int j = 0; j < 128; j += 4) {                                       \
    float4 wl = *(const float4*)&sWl[j];                                   \
    float4 wr = *(const float4*)&sWr[j];                                   \
    float4 we = *(const float4*)&sWe[j];                                   \
    float4 bb = *(const float4*)&sB[j];                                    \
    float4 at = *(const float4*)&sAt[j];                                   \
    STEP4(x, a00, a01, a02, a03)                                           \
    STEP4(y, a00, a01, a02, a03)                                           \
    STEP4(z, a00, a01, a02, a03)                                           \
    STEP4(w, a00, a01, a02, a03)                                           \
  }                                                                        \
  _Pragma("unroll 2")                                                      \
  for (int j = 128; j < 256; j += 4) {                                     \
    float4 wl = *(const float4*)&sWl[j];                                   \
    float4 wr = *(const float4*)&sWr[j];                                   \
    float4 we = *(const float4*)&sWe[j];                                   \
    float4 bb = *(const float4*)&sB[j];                                    \
    float4 at = *(const float4*)&sAt[j];                                   \
    STEP4(x, a10, a11, a12, a13)                                           \
    STEP4(y, a10, a11, a12, a13)                                           \
    STEP4(z, a10, a11, a12, a13)                                           \
    STEP4(w, a10, a11, a12, a13)                                           \
  }                                                                        \
  float4 c0 = *(const float4*)&ws[WS_C];                                   \
  float4 c1 = *(const float4*)&ws[WS_C + 4];

// ---------------- k0: init + attention-dot constants ----------------
extern "C" __global__ __launch_bounds__(256)
void k0_init(float* __restrict__ ws,
             const float* __restrict__ att, const float* __restrict__ Wl,
             const float* __restrict__ Wr, const float* __restrict__ We,
             const float* __restrict__ bl, const float* __restrict__ br,
             float* __restrict__ out, int dense)
{
  int tid = blockIdx.x * 256 + threadIdx.x;
  int nt = gridDim.x * 256;
  if (dense) {
    if (tid < 14) ws[WS_MOM + tid] = 0.f;
  } else {
    for (int i = tid; i < 4 * NN; i += nt) ws[WS_ACC + i] = 0.f;
    for (int i = tid; i < 256; i += nt) ws[WS_BNSUM + i] = 0.f;
  }
  for (int i = tid; i < NG * 128; i += nt) out[i] = 0.f;
  if (blockIdx.x == 0) {
    __shared__ float red[4][256];
    int t = threadIdx.x;                    // t = h*128 + d
    float a = att[t];
    red[0][t] = a * Wl[t];
    red[1][t] = a * Wr[t];
    red[2][t] = a * We[t];
    red[3][t] = a * (bl[t] + br[t]);
    __syncthreads();
    if (t < 8) {
      int k = t >> 1, h = t & 1;
      float s = 0.f;
      for (int d = 0; d < 128; ++d) s += red[k][h * 128 + d];
      ws[WS_C + h * 4 + k] = s;
    }
  }
}

// ---------------- k_score: fused score+exp + per-block bucket histogram ----------------
// Round-2 post-mortem: ke's 800K device-scope atomicExch were the wall
// (~25MB of HBM RMW traffic, ~5 exch/cycle device-wide = 68us). This kernel
// has ZERO global atomics: records {e0,e1,xs,dst} stream out (12.8MB), and
// the dst>>8 histogram is LDS-only. No early return: __syncthreads below.
extern "C" __global__ __launch_bounds__(256, 2)
void k_score(const int* __restrict__ ei, const float* __restrict__ x,
             const float* __restrict__ eattr,
             const float* __restrict__ Wl, const float* __restrict__ Wr,
             const float* __restrict__ We, const float* __restrict__ bl,
             const float* __restrict__ br, const float* __restrict__ att,
             float* __restrict__ ws)
{
  SMEM_WEIGHTS_DECL
  __shared__ unsigned cnt[256];
  cnt[threadIdx.x] = 0u;
  SMEM_WEIGHTS_LOAD                       // ends with __syncthreads()
  int base = (blockIdx.x * 256 + threadIdx.x) * 4;
  if (base < NE) {
    SCORE_CORE
    atomicAdd(&cnt[((unsigned)dd4.x) >> 8], 1u);
    atomicAdd(&cnt[((unsigned)dd4.y) >> 8], 1u);
    atomicAdd(&cnt[((unsigned)dd4.z) >> 8], 1u);
    atomicAdd(&cnt[((unsigned)dd4.w) >> 8], 1u);
    SCORE_LOOPS
    float4* rec0 = (float4*)(ws + WS_REC0);
    float s0, s1;
    SCORES(xs0, xd0, ae0, a00, a10, s0, s1)
    rec0[base + 0] = make_float4(__expf(s0), __expf(s1), xs0, __uint_as_float((unsigned)dd4.x));
    SCORES(xs1, xd1, ae1, a01, a11, s0, s1)
    rec0[base + 1] = make_float4(__expf(s0), __expf(s1), xs1, __uint_as_float((unsigned)dd4.y));
    SCORES(xs2, xd2, ae2, a02, a12, s0, s1)
    rec0[base + 2] = make_float4(__expf(s0), __expf(s1), xs2, __uint_as_float((unsigned)dd4.z));
    SCORES(xs3, xd3, ae3, a03, a13, s0, s1)
    rec0[base + 3] = make_float4(__expf(s0), __expf(s1), xs3, __uint_as_float((unsigned)dd4.w));
  }
  __syncthreads();
  unsigned* counts = (unsigned*)(ws + WS_CNT);   // bucket-major [256][NBLK]
  counts[(size_t)threadIdx.x * NBLK + blockIdx.x] = cnt[threadIdx.x];
}

// ---------------- k_scan: per-bucket block offsets + bucket bases ----------------
// Thread b owns bucket b's CONTIGUOUS row counts[b][0..NBLK): in-place
// exclusive running sum, then a 256-wide LDS scan for bucket bases.
extern "C" __global__ __launch_bounds__(256)
void k_scan(float* __restrict__ ws)
{
  int b = threadIdx.x;
  unsigned* counts = (unsigned*)(ws + WS_CNT);
  unsigned* row = counts + (size_t)b * NBLK;
  unsigned run = 0;
#pragma unroll 4
  for (int k = 0; k < NBLK; ++k) { unsigned t = row[k]; row[k] = run; run += t; }
  __shared__ unsigned sc[256];
  sc[b] = run;
  __syncthreads();
  for (int o = 1; o < 256; o <<= 1) {
    unsigned v = (b >= o) ? sc[b - o] : 0u;
    __syncthreads();
    sc[b] += v;
    __syncthreads();
  }
  unsigned* ex = (unsigned*)(ws + WS_EX);
  ex[b] = sc[b] - run;                    // exclusive prefix
  if (b == 255) ex[256] = sc[b];          // == NE
}

// ---------------- k_scatter: place records into bucket regions ----------------
// Positions: ex[b] + counts[b][blk] + (LDS rank) — a permutation of [0,NE).
// Same-block same-bucket writes get consecutive slots -> line-sized runs.
extern "C" __global__ __launch_bounds__(256)
void k_scatter(float* __restrict__ ws)
{
  __shared__ unsigned soff[256];
  int blk = blockIdx.x, tid = threadIdx.x;
  const unsigned* counts = (const unsigned*)(ws + WS_CNT);
  const unsigned* ex = (const unsigned*)(ws + WS_EX);
  soff[tid] = ex[tid] + counts[(size_t)tid * NBLK + blk];
  __syncthreads();
  const float4* rec0 = (const float4*)(ws + WS_REC0);
  float4* srt = (float4*)(ws + WS_SORT);
  int e0i = blk * CB + tid;
#pragma unroll
  for (int i = 0; i < 4; ++i) {
    int e = e0i + i * 256;
    if (e < NE) {
      float4 r = rec0[e];
      unsigned d = __float_as_uint(r.w);
      unsigned p = atomicAdd(&soff[d >> 8], 1u);
      srt[p] = r;
    }
  }
}

// ---------------- k_gather: per-bucket coalesced reduce + BN moments ----------------
// One block per bucket (256 nodes): stream ~4K records coalesced, LDS
// atomicAdd into acc[256][4], write WS_ACC, fused 14-moment reduction.
extern "C" __global__ __launch_bounds__(256)
void k_gather(float* __restrict__ ws)
{
  int b = blockIdx.x;
  const int t = threadIdx.x;
  __shared__ float acc[1024];
  acc[t] = 0.f; acc[256 + t] = 0.f; acc[512 + t] = 0.f; acc[768 + t] = 0.f;
  __syncthreads();
  const unsigned* ex = (const unsigned*)(ws + WS_EX);
  int lo = (int)ex[b], hi = (int)ex[b + 1];
  const float4* srt = (const float4*)(ws + WS_SORT);
  for (int i = lo + t; i < hi; i += 256) {
    float4 r = srt[i];
    int l4 = (int)(__float_as_uint(r.w) & 255u) * 4;
    atomicAdd(&acc[l4 + 0], r.x);
    atomicAdd(&acc[l4 + 1], r.y);
    atomicAdd(&acc[l4 + 2], r.x * r.z);
    atomicAdd(&acc[l4 + 3], r.y * r.z);
  }
  __syncthreads();
  int n = (b << 8) + t;
  float f1 = 0.f, f2 = 0.f, f3 = 0.f, f4 = 0.f;
  if (n < NN) {
    float4 A = make_float4(acc[t * 4], acc[t * 4 + 1], acc[t * 4 + 2], acc[t * 4 + 3]);
    *(float4*)&ws[WS_ACC + 4 * n] = A;
    float r0 = 1.f / (A.x + 1e-16f);
    float r1 = 1.f / (A.y + 1e-16f);
    f1 = A.x * r0; f2 = A.z * r0; f3 = A.y * r1; f4 = A.w * r1;
  }
  // moments: S1..S4, M11,M12,M13,M14,M22,M23,M24,M33,M34,M44
  float pm[14] = { f1, f2, f3, f4,
                   f1*f1, f1*f2, f1*f3, f1*f4,
                   f2*f2, f2*f3, f2*f4,
                   f3*f3, f3*f4, f4*f4 };
#pragma unroll
  for (int k = 0; k < 14; ++k) {
    float v = pm[k];
#pragma unroll
    for (int m = 32; m >= 1; m >>= 1) v += __shfl_xor(v, m);
    pm[k] = v;
  }
  __shared__ float smom[56];
  int wid = t >> 6, lane = t & 63;
  if (lane == 0) {
#pragma unroll
    for (int k = 0; k < 14; ++k) smom[wid * 14 + k] = pm[k];
  }
  __syncthreads();
  if (t < 14) {
    float s = smom[t] + smom[14 + t] + smom[28 + t] + smom[42 + t];
    atomicAdd(&ws[WS_MOM + t], s);
  }
}

// ---------------- k4m: BN from moments + leaky_relu + graph pooling ----------------
extern "C" __global__ __launch_bounds__(256)
void k4m_pool(const int* __restrict__ batch,
              const float* __restrict__ Wl, const float* __restrict__ bl,
              const float* __restrict__ bias, const float* __restrict__ gamma,
              const float* __restrict__ beta,
              float* __restrict__ ws, float* __restrict__ out)
{
  const int CHUNK = (NN + (int)gridDim.x - 1) / (int)gridDim.x;
  int n0 = blockIdx.x * CHUNK;
  if (n0 >= NN) return;
  int n1 = n0 + CHUNK; if (n1 > NN) n1 = NN;
  int t = threadIdx.x;
  int d = t & 127;
  int row = t >> 7;
  float S1 = ws[WS_MOM + 0], S2 = ws[WS_MOM + 1];
  float S3 = ws[WS_MOM + 2], S4 = ws[WS_MOM + 3];
  float M11 = ws[WS_MOM + 4], M12 = ws[WS_MOM + 5], M13 = ws[WS_MOM + 6];
  float M14 = ws[WS_MOM + 7], M22 = ws[WS_MOM + 8], M23 = ws[WS_MOM + 9];
  float M24 = ws[WS_MOM + 10], M33 = ws[WS_MOM + 11], M34 = ws[WS_MOM + 12];
  float M44 = ws[WS_MOM + 13];
  float g1 = 0.5f * bl[d], g2 = 0.5f * Wl[d];
  float g3 = 0.5f * bl[128 + d], g4 = 0.5f * Wl[128 + d];
  float g5 = bias[d];
  const float invN = 1.f / (float)NN;
  float dotS = g1 * S1 + g2 * S2 + g3 * S3 + g4 * S4;
  float mean = (dotS + (float)NN * g5) * invN;
  float sumsq = g1*g1*M11 + g2*g2*M22 + g3*g3*M33 + g4*g4*M44
              + 2.f*(g1*g2*M12 + g1*g3*M13 + g1*g4*M14
                   + g2*g3*M23 + g2*g4*M24 + g3*g4*M34)
              + 2.f*g5*dotS + (float)NN*g5*g5;
  float var = fmaf(sumsq, invN, -mean * mean);
  float scale = gamma[d] * rsqrtf(var + 1e-5f);
  float shift = fmaf(-mean, scale, beta[d]);
  __shared__ float pool[4][128];
  for (int i = t; i < 512; i += 256) ((float*)pool)[i] = 0.f;
  __syncthreads();
  int g0 = batch[n0];
  for (int n = n0 + row; n < n1; n += 2) {
    float4 a = *(const float4*)&ws[WS_ACC + 4 * n];
    float r0 = 1.f / (a.x + 1e-16f);
    float r1 = 1.f / (a.y + 1e-16f);
    float o = g1 * (a.x * r0) + g2 * (a.z * r0)
            + g3 * (a.y * r1) + g4 * (a.w * r1) + g5;
    float v = fmaf(o, scale, shift);
    v = v > 0.f ? v : 0.01f * v;
    int g = batch[n];
    int slot = g - g0;                    // >= 0: batch is sorted
    if (slot < 4) atomicAdd(&pool[slot][d], v);
    else atomicAdd(&out[g * 128 + d], v);
  }
  __syncthreads();
  for (int i = t; i < 512; i += 256) {
    int slot = i >> 7, dd = i & 127;
    int g = g0 + slot;
    float v = pool[slot][dd];
    if (g < NG && v != 0.f) atomicAdd(&out[g * 128 + dd], v);
  }
}

// ==================== fallback path (small ws): direct atomics + BNSUM ====================
extern "C" __global__ __launch_bounds__(256)
void k12f(const int* __restrict__ ei, const float* __restrict__ x,
          const float* __restrict__ eattr,
          const float* __restrict__ Wl, const float* __restrict__ Wr,
          const float* __restrict__ We, const float* __restrict__ bl,
          const float* __restrict__ br, const float* __restrict__ att,
          float* __restrict__ ws)
{
  SMEM_WEIGHTS_DECL
  SMEM_WEIGHTS_LOAD
  int base = (blockIdx.x * 256 + threadIdx.x) * 4;
  if (base >= NE) return;
  SCORE_CORE
  SCORE_LOOPS
  float* acc = ws + WS_ACC;
  float s0, s1;
#define EPI2(xs_, xd_, ae_, accA, accB, dsti)                              \
  { SCORES(xs_, xd_, ae_, accA, accB, s0, s1)                              \
    float e0 = __expf(s0), e1 = __expf(s1);                                \
    float* a = &acc[4 * dsti];                                             \
    atomicAdd(a + 0, e0); atomicAdd(a + 1, e1);                            \
    atomicAdd(a + 2, e0 * xs_); atomicAdd(a + 3, e1 * xs_); }
  EPI2(xs0, xd0, ae0, a00, a10, dd4.x)
  EPI2(xs1, xd1, ae1, a01, a11, dd4.y)
  EPI2(xs2, xd2, ae2, a02, a12, dd4.z)
  EPI2(xs3, xd3, ae3, a03, a13, dd4.w)
#undef EPI2
}

__device__ __forceinline__ float node_out4(float4 a, float wl0, float wl1,
                                           float b0, float b1, float bs)
{
  float r0 = 1.f / (a.x + 1e-16f);
  float r1 = 1.f / (a.y + 1e-16f);
  return 0.5f * (fmaf(wl0, a.z * r0, b0 * (a.x * r0)) +
                 fmaf(wl1, a.w * r1, b1 * (a.y * r1))) + bs;
}

extern "C" __global__ __launch_bounds__(256)
void k3_stats(const float* __restrict__ Wl, const float* __restrict__ bl,
              const float* __restrict__ bias, float* __restrict__ ws)
{
  int d = threadIdx.x & 127;
  int row = threadIdx.x >> 7;
  float wl0 = Wl[d], wl1 = Wl[128 + d];
  float b0 = bl[d], b1 = bl[128 + d];
  float bs = bias[d];
  float sum = 0.f, sq = 0.f;
  for (int n = blockIdx.x * 2 + row; n < NN; n += gridDim.x * 2) {
    float4 a = *(const float4*)&ws[WS_ACC + 4 * n];
    float o = node_out4(a, wl0, wl1, b0, b1, bs);
    sum += o;
    sq = fmaf(o, o, sq);
  }
  __shared__ float l1[256], l2[256];
  l1[threadIdx.x] = sum; l2[threadIdx.x] = sq;
  __syncthreads();
  if (row == 0) {
    atomicAdd(&ws[WS_BNSUM + d], l1[d] + l1[128 + d]);
    atomicAdd(&ws[WS_BNSQ + d], l2[d] + l2[128 + d]);
  }
}

extern "C" __global__ __launch_bounds__(256)
void k4_pool(const int* __restrict__ batch,
             const float* __restrict__ Wl, const float* __restrict__ bl,
             const float* __restrict__ bias, const float* __restrict__ gamma,
             const float* __restrict__ beta,
             float* __restrict__ ws, float* __restrict__ out)
{
  const int CHUNK = (NN + (int)gridDim.x - 1) / (int)gridDim.x;
  int n0 = blockIdx.x * CHUNK;
  if (n0 >= NN) return;
  int n1 = n0 + CHUNK; if (n1 > NN) n1 = NN;
  int d = threadIdx.x & 127;
  int row = threadIdx.x >> 7;
  const float invN = 1.f / (float)NN;
  float mean = ws[WS_BNSUM + d] * invN;
  float var = fmaf(ws[WS_BNSQ + d], invN, -mean * mean);
  float scale = gamma[d] * rsqrtf(var + 1e-5f);
  float shift = fmaf(-mean, scale, beta[d]);
  float wl0 = Wl[d], wl1 = Wl[128 + d];
  float b0 = bl[d], b1 = bl[128 + d];
  float bs = bias[d];
  __shared__ float pool[4][128];
  for (int i = threadIdx.x; i < 512; i += 256) ((float*)pool)[i] = 0.f;
  __syncthreads();
  int g0 = batch[n0];
  for (int n = n0 + row; n < n1; n += 2) {
    float4 a = *(const float4*)&ws[WS_ACC + 4 * n];
    float o = node_out4(a, wl0, wl1, b0, b1, bs);
    float v = fmaf(o, scale, shift);
    v = v > 0.f ? v : 0.01f * v;
    int g = batch[n];
    int slot = g - g0;
    if (slot < 4) atomicAdd(&pool[slot][d], v);
    else atomicAdd(&out[g * 128 + d], v);
  }
  __syncthreads();
  for (int i = threadIdx.x; i < 512; i += 256) {
    int slot = i >> 7, dd = i & 127;
    int g = g0 + slot;
    float v = pool[slot][dd];
    if (g < NG && v != 0.f) atomicAdd(&out[g * 128 + dd], v);
  }
}

extern "C" void kernel_launch(void* const* d_in, const int* in_sizes, int n_in,
                              void* d_out, int out_size, void* d_ws, size_t ws_size,
                              hipStream_t stream) {
  const float* x     = (const float*)d_in[0];
  const int*   ei    = (const int*)d_in[1];
  const float* eattr = (const float*)d_in[2];
  const int*   batch = (const int*)d_in[3];
  const float* Wl    = (const float*)d_in[4];
  const float* bl    = (const float*)d_in[5];
  const float* Wr    = (const float*)d_in[6];
  const float* br    = (const float*)d_in[7];
  const float* We    = (const float*)d_in[8];
  const float* att   = (const float*)d_in[9];
  const float* bias  = (const float*)d_in[10];
  const float* gam   = (const float*)d_in[11];
  const float* bet   = (const float*)d_in[12];
  float* ws  = (float*)d_ws;
  float* out = (float*)d_out;

  const bool dense = (ws_size >= WS_NEED_BYTES);

  hipLaunchKernelGGL(k0_init, dim3(32), dim3(256), 0, stream,
                     ws, att, Wl, Wr, We, bl, br, out, dense ? 1 : 0);
  if (dense) {
    hipLaunchKernelGGL(k_score, dim3(NBLK), dim3(256), 0, stream,
                       ei, x, eattr, Wl, Wr, We, bl, br, att, ws);
    hipLaunchKernelGGL(k_scan, dim3(1), dim3(256), 0, stream, ws);
    hipLaunchKernelGGL(k_scatter, dim3(NBLK), dim3(256), 0, stream, ws);
    hipLaunchKernelGGL(k_gather, dim3(NBUCK), dim3(256), 0, stream, ws);
    hipLaunchKernelGGL(k4m_pool, dim3(256), dim3(256), 0, stream,
                       batch, Wl, bl, bias, gam, bet, ws, out);
  } else {
    hipLaunchKernelGGL(k12f, dim3((NE / 4 + 255) / 256), dim3(256), 0, stream,
                       ei, x, eattr, Wl, Wr, We, bl, br, att, ws);
    hipLaunchKernelGGL(k3_stats, dim3(256), dim3(256), 0, stream,
                       Wl, bl, bias, ws);
    hipLaunchKernelGGL(k4_pool, dim3(256), dim3(256), 0, stream,
                       batch, Wl, bl, bias, gam, bet, ws, out);
  }
}

// Round 4
// 200.139 us; speedup vs baseline: 1.9420x; 1.9420x over previous
//
#include <hip/hip_runtime.h>
#include <math.h>

#define NN 50000
#define NE 800000
#define NG 64

// ---------------- sort pipeline geometry ----------------
#define CB    1024                        // edges per score/scatter block
#define NBLK  782                         // ceil(NE / CB)
#define NBUCK 196                         // ceil(NN / 256), bucket = dst >> 8

static_assert(NBLK * CB >= NE, "chunk cover");
static_assert((NBUCK - 1) == (NN - 1) / 256, "bucket count");

// ---------------- ws layout (float offsets) ----------------
#define WS_C     0                       // 8 floats: [h*4 + {att.Wl, att.Wr, att.We, att.B}]
#define WS_ACC   16                      // 4*NN floats: {den0,den1,t10,t11} per node (float4)
#define WS_BNSUM (WS_ACC + 4*NN)         // 128 (fallback path)
#define WS_BNSQ  (WS_BNSUM + 128)        // 128 (fallback path)
#define WS_MOM   WS_BNSUM                // dense path: 14 floats (overlaps BNSUM, paths exclusive)
#define WS_EX    (WS_BNSQ + 128)         // 257 u32 bucket exclusive offsets
#define WS_TOT   (WS_EX + 272)           // 256 u32 bucket totals (scan level 2 input)
#define WS_CNT   (WS_TOT + 256)          // 256*NBLK u32, bucket-major [b][blk]
#define WS_REC0  (WS_CNT + 256*NBLK)     // NE float4 = {e0, e1, xs, asfloat(dst)}
#define WS_SORT  (WS_REC0 + 4*NE)        // NE float4, bucket-partitioned
#define WS_END   (WS_SORT + 4*NE)
#define WS_NEED_BYTES ((size_t)WS_END * 4 + 256)

static_assert(((WS_REC0 * 4) % 16) == 0, "rec0 16B alignment");
static_assert(((WS_SORT * 4) % 16) == 0, "sort 16B alignment");
static_assert(NE % 4 == 0, "edge unroll");

// ---------------- shared score machinery ----------------
#define STEP(wl_, wr_, we_, bb_, at_, xs_, xd_, ae_, acc_)                 \
  { float tt = fmaf(we_, ae_, bb_); tt = fmaf(wr_, xd_, tt);               \
    tt = fmaf(wl_, xs_, tt); acc_ = fmaf(fabsf(tt), at_, acc_); }

#define SMEM_WEIGHTS_DECL                                                  \
  __shared__ __align__(16) float sWl[256], sWr[256], sWe[256], sB[256], sAt[256];

#define SMEM_WEIGHTS_LOAD                                                  \
  { int t_ = threadIdx.x;                                                  \
    sWl[t_] = Wl[t_]; sWr[t_] = Wr[t_]; sWe[t_] = We[t_];                  \
    sB[t_] = bl[t_] + br[t_]; sAt[t_] = att[t_]; }                         \
  __syncthreads();

#define SCORES(xs_, xd_, ae_, accA, accB, out0, out1)                      \
  { float lin0 = fmaf(c0.x, xs_, fmaf(c0.y, xd_, fmaf(c0.z, ae_, c0.w))); \
    out0 = fmaf(0.4f, accA, 0.6f * lin0);                                  \
    float lin1 = fmaf(c1.x, xs_, fmaf(c1.y, xd_, fmaf(c1.z, ae_, c1.w))); \
    out1 = fmaf(0.4f, accB, 0.6f * lin1); }

// ---- 4-edge score core (dense k_score AND fallback k12f) ----
#define STEP4(c, q0, q1, q2, q3)                                           \
  STEP(wl.c, wr.c, we.c, bb.c, at.c, xs0, xd0, ae0, q0)                    \
  STEP(wl.c, wr.c, we.c, bb.c, at.c, xs1, xd1, ae1, q1)                    \
  STEP(wl.c, wr.c, we.c, bb.c, at.c, xs2, xd2, ae2, q2)                    \
  STEP(wl.c, wr.c, we.c, bb.c, at.c, xs3, xd3, ae3, q3)

#define SCORE_CORE                                                         \
  int4 s4 = *(const int4*)&ei[base];                                       \
  int4 dd4 = *(const int4*)&ei[NE + base];                                 \
  float4 ae4 = *(const float4*)&eattr[base];                               \
  float xs0 = x[s4.x], xs1 = x[s4.y], xs2 = x[s4.z], xs3 = x[s4.w];        \
  float xd0 = x[dd4.x], xd1 = x[dd4.y], xd2 = x[dd4.z], xd3 = x[dd4.w];    \
  float ae0 = ae4.x, ae1 = ae4.y, ae2 = ae4.z, ae3 = ae4.w;

#define SCORE_LOOPS                                                        \
  float a00 = 0.f, a01 = 0.f, a02 = 0.f, a03 = 0.f;                        \
  float a10 = 0.f, a11 = 0.f, a12 = 0.f, a13 = 0.f;                        \
  _Pragma("unroll 2")                                                      \
  for (int j = 0; j < 128; j += 4) {                                       \
    float4 wl = *(const float4*)&sWl[j];                                   \
    float4 wr = *(const float4*)&sWr[j];                                   \
    float4 we = *(const float4*)&sWe[j];                                   \
    float4 bb = *(const float4*)&sB[j];                                    \
    float4 at = *(const float4*)&sAt[j];                                   \
    STEP4(x, a00, a01, a02, a03)                                           \
    STEP4(y, a00, a01, a02, a03)                                           \
    STEP4(z, a00, a01, a02, a03)                                           \
    STEP4(w, a00, a01, a02, a03)                                           \
  }                                                                        \
  _Pragma("unroll 2")                                                      \
  for (int j = 128; j < 256; j += 4) {                                     \
    float4 wl = *(const float4*)&sWl[j];                                   \
    float4 wr = *(const float4*)&sWr[j];                                   \
    float4 we = *(const float4*)&sWe[j];                                   \
    float4 bb = *(const float4*)&sB[j];                                    \
    float4 at = *(const float4*)&sAt[j];                                   \
    STEP4(x, a10, a11, a12, a13)                                           \
    STEP4(y, a10, a11, a12, a13)                                           \
    STEP4(z, a10, a11, a12, a13)                                           \
    STEP4(w, a10, a11, a12, a13)                                           \
  }                                                                        \
  float4 c0 = *(const float4*)&ws[WS_C];                                   \
  float4 c1 = *(const float4*)&ws[WS_C + 4];

// ---------------- k0: init + attention-dot constants ----------------
extern "C" __global__ __launch_bounds__(256)
void k0_init(float* __restrict__ ws,
             const float* __restrict__ att, const float* __restrict__ Wl,
             const float* __restrict__ Wr, const float* __restrict__ We,
             const float* __restrict__ bl, const float* __restrict__ br,
             float* __restrict__ out, int dense)
{
  int tid = blockIdx.x * 256 + threadIdx.x;
  int nt = gridDim.x * 256;
  if (dense) {
    if (tid < 14) ws[WS_MOM + tid] = 0.f;
  } else {
    for (int i = tid; i < 4 * NN; i += nt) ws[WS_ACC + i] = 0.f;
    for (int i = tid; i < 256; i += nt) ws[WS_BNSUM + i] = 0.f;
  }
  for (int i = tid; i < NG * 128; i += nt) out[i] = 0.f;
  if (blockIdx.x == 0) {
    __shared__ float red[4][256];
    int t = threadIdx.x;                    // t = h*128 + d
    float a = att[t];
    red[0][t] = a * Wl[t];
    red[1][t] = a * Wr[t];
    red[2][t] = a * We[t];
    red[3][t] = a * (bl[t] + br[t]);
    __syncthreads();
    if (t < 8) {
      int k = t >> 1, h = t & 1;
      float s = 0.f;
      for (int d = 0; d < 128; ++d) s += red[k][h * 128 + d];
      ws[WS_C + h * 4 + k] = s;
    }
  }
}

// ---------------- k_score: fused score+exp + per-block bucket histogram ----------------
extern "C" __global__ __launch_bounds__(256, 2)
void k_score(const int* __restrict__ ei, const float* __restrict__ x,
             const float* __restrict__ eattr,
             const float* __restrict__ Wl, const float* __restrict__ Wr,
             const float* __restrict__ We, const float* __restrict__ bl,
             const float* __restrict__ br, const float* __restrict__ att,
             float* __restrict__ ws)
{
  SMEM_WEIGHTS_DECL
  __shared__ unsigned cnt[256];
  cnt[threadIdx.x] = 0u;
  SMEM_WEIGHTS_LOAD                       // ends with __syncthreads()
  int base = (blockIdx.x * 256 + threadIdx.x) * 4;
  if (base < NE) {
    SCORE_CORE
    atomicAdd(&cnt[((unsigned)dd4.x) >> 8], 1u);
    atomicAdd(&cnt[((unsigned)dd4.y) >> 8], 1u);
    atomicAdd(&cnt[((unsigned)dd4.z) >> 8], 1u);
    atomicAdd(&cnt[((unsigned)dd4.w) >> 8], 1u);
    SCORE_LOOPS
    float4* rec0 = (float4*)(ws + WS_REC0);
    float s0, s1;
    SCORES(xs0, xd0, ae0, a00, a10, s0, s1)
    rec0[base + 0] = make_float4(__expf(s0), __expf(s1), xs0, __uint_as_float((unsigned)dd4.x));
    SCORES(xs1, xd1, ae1, a01, a11, s0, s1)
    rec0[base + 1] = make_float4(__expf(s0), __expf(s1), xs1, __uint_as_float((unsigned)dd4.y));
    SCORES(xs2, xd2, ae2, a02, a12, s0, s1)
    rec0[base + 2] = make_float4(__expf(s0), __expf(s1), xs2, __uint_as_float((unsigned)dd4.z));
    SCORES(xs3, xd3, ae3, a03, a13, s0, s1)
    rec0[base + 3] = make_float4(__expf(s0), __expf(s1), xs3, __uint_as_float((unsigned)dd4.w));
  }
  __syncthreads();
  unsigned* counts = (unsigned*)(ws + WS_CNT);   // bucket-major [256][NBLK]
  counts[(size_t)threadIdx.x * NBLK + blockIdx.x] = cnt[threadIdx.x];
}

// ---------------- k_scan1: per-bucket row scan (256 blocks, coalesced) ----------------
// Round-3 post-mortem: the single-block serial scan was 203us (one CU,
// 64 uncoalesced lines per wave-step, 0.07% HBM). One block PER BUCKET ROW:
// contiguous 782-entry row scanned with a 256-wide chunked LDS scan.
extern "C" __global__ __launch_bounds__(256)
void k_scan1(float* __restrict__ ws)
{
  int b = blockIdx.x;
  int t = threadIdx.x;
  unsigned* row = (unsigned*)(ws + WS_CNT) + (size_t)b * NBLK;
  __shared__ unsigned sc[256];
  unsigned carry = 0;
  for (int c = 0; c < NBLK; c += 256) {
    int k = c + t;
    unsigned v = (k < NBLK) ? row[k] : 0u;
    sc[t] = v;
    __syncthreads();
    for (int o = 1; o < 256; o <<= 1) {
      unsigned u = (t >= o) ? sc[t - o] : 0u;
      __syncthreads();
      sc[t] += u;
      __syncthreads();
    }
    unsigned incl = sc[t];
    if (k < NBLK) row[k] = carry + incl - v;   // exclusive within bucket
    unsigned total = sc[255];
    __syncthreads();                            // before sc reuse
    carry += total;
  }
  if (t == 0) ((unsigned*)(ws + WS_TOT))[b] = carry;
}

// ---------------- k_scan2: bucket bases from totals (tiny) ----------------
extern "C" __global__ __launch_bounds__(256)
void k_scan2(float* __restrict__ ws)
{
  int b = threadIdx.x;
  unsigned v = ((const unsigned*)(ws + WS_TOT))[b];
  __shared__ unsigned sc[256];
  sc[b] = v;
  __syncthreads();
  for (int o = 1; o < 256; o <<= 1) {
    unsigned u = (b >= o) ? sc[b - o] : 0u;
    __syncthreads();
    sc[b] += u;
    __syncthreads();
  }
  unsigned* ex = (unsigned*)(ws + WS_EX);
  ex[b] = sc[b] - v;                      // exclusive prefix
  if (b == 255) ex[256] = sc[b];          // == NE
}

// ---------------- k_scatter: place records into bucket regions ----------------
extern "C" __global__ __launch_bounds__(256)
void k_scatter(float* __restrict__ ws)
{
  __shared__ unsigned soff[256];
  int blk = blockIdx.x, tid = threadIdx.x;
  const unsigned* counts = (const unsigned*)(ws + WS_CNT);
  const unsigned* ex = (const unsigned*)(ws + WS_EX);
  soff[tid] = ex[tid] + counts[(size_t)tid * NBLK + blk];
  __syncthreads();
  const float4* rec0 = (const float4*)(ws + WS_REC0);
  float4* srt = (float4*)(ws + WS_SORT);
  int e0i = blk * CB + tid;
#pragma unroll
  for (int i = 0; i < 4; ++i) {
    int e = e0i + i * 256;
    if (e < NE) {
      float4 r = rec0[e];
      unsigned d = __float_as_uint(r.w);
      unsigned p = atomicAdd(&soff[d >> 8], 1u);
      srt[p] = r;
    }
  }
}

// ---------------- k_gather: per-bucket coalesced reduce + BN moments ----------------
extern "C" __global__ __launch_bounds__(256)
void k_gather(float* __restrict__ ws)
{
  int b = blockIdx.x;
  const int t = threadIdx.x;
  __shared__ float acc[1024];
  acc[t] = 0.f; acc[256 + t] = 0.f; acc[512 + t] = 0.f; acc[768 + t] = 0.f;
  __syncthreads();
  const unsigned* ex = (const unsigned*)(ws + WS_EX);
  int lo = (int)ex[b], hi = (int)ex[b + 1];
  const float4* srt = (const float4*)(ws + WS_SORT);
  for (int i = lo + t; i < hi; i += 256) {
    float4 r = srt[i];
    int l4 = (int)(__float_as_uint(r.w) & 255u) * 4;
    atomicAdd(&acc[l4 + 0], r.x);
    atomicAdd(&acc[l4 + 1], r.y);
    atomicAdd(&acc[l4 + 2], r.x * r.z);
    atomicAdd(&acc[l4 + 3], r.y * r.z);
  }
  __syncthreads();
  int n = (b << 8) + t;
  float f1 = 0.f, f2 = 0.f, f3 = 0.f, f4 = 0.f;
  if (n < NN) {
    float4 A = make_float4(acc[t * 4], acc[t * 4 + 1], acc[t * 4 + 2], acc[t * 4 + 3]);
    *(float4*)&ws[WS_ACC + 4 * n] = A;
    float r0 = 1.f / (A.x + 1e-16f);
    float r1 = 1.f / (A.y + 1e-16f);
    f1 = A.x * r0; f2 = A.z * r0; f3 = A.y * r1; f4 = A.w * r1;
  }
  // moments: S1..S4, M11,M12,M13,M14,M22,M23,M24,M33,M34,M44
  float pm[14] = { f1, f2, f3, f4,
                   f1*f1, f1*f2, f1*f3, f1*f4,
                   f2*f2, f2*f3, f2*f4,
                   f3*f3, f3*f4, f4*f4 };
#pragma unroll
  for (int k = 0; k < 14; ++k) {
    float v = pm[k];
#pragma unroll
    for (int m = 32; m >= 1; m >>= 1) v += __shfl_xor(v, m);
    pm[k] = v;
  }
  __shared__ float smom[56];
  int wid = t >> 6, lane = t & 63;
  if (lane == 0) {
#pragma unroll
    for (int k = 0; k < 14; ++k) smom[wid * 14 + k] = pm[k];
  }
  __syncthreads();
  if (t < 14) {
    float s = smom[t] + smom[14 + t] + smom[28 + t] + smom[42 + t];
    atomicAdd(&ws[WS_MOM + t], s);
  }
}

// ---------------- k4m: BN from moments + leaky_relu + graph pooling ----------------
extern "C" __global__ __launch_bounds__(256)
void k4m_pool(const int* __restrict__ batch,
              const float* __restrict__ Wl, const float* __restrict__ bl,
              const float* __restrict__ bias, const float* __restrict__ gamma,
              const float* __restrict__ beta,
              float* __restrict__ ws, float* __restrict__ out)
{
  const int CHUNK = (NN + (int)gridDim.x - 1) / (int)gridDim.x;
  int n0 = blockIdx.x * CHUNK;
  if (n0 >= NN) return;
  int n1 = n0 + CHUNK; if (n1 > NN) n1 = NN;
  int t = threadIdx.x;
  int d = t & 127;
  int row = t >> 7;
  float S1 = ws[WS_MOM + 0], S2 = ws[WS_MOM + 1];
  float S3 = ws[WS_MOM + 2], S4 = ws[WS_MOM + 3];
  float M11 = ws[WS_MOM + 4], M12 = ws[WS_MOM + 5], M13 = ws[WS_MOM + 6];
  float M14 = ws[WS_MOM + 7], M22 = ws[WS_MOM + 8], M23 = ws[WS_MOM + 9];
  float M24 = ws[WS_MOM + 10], M33 = ws[WS_MOM + 11], M34 = ws[WS_MOM + 12];
  float M44 = ws[WS_MOM + 13];
  float g1 = 0.5f * bl[d], g2 = 0.5f * Wl[d];
  float g3 = 0.5f * bl[128 + d], g4 = 0.5f * Wl[128 + d];
  float g5 = bias[d];
  const float invN = 1.f / (float)NN;
  float dotS = g1 * S1 + g2 * S2 + g3 * S3 + g4 * S4;
  float mean = (dotS + (float)NN * g5) * invN;
  float sumsq = g1*g1*M11 + g2*g2*M22 + g3*g3*M33 + g4*g4*M44
              + 2.f*(g1*g2*M12 + g1*g3*M13 + g1*g4*M14
                   + g2*g3*M23 + g2*g4*M24 + g3*g4*M34)
              + 2.f*g5*dotS + (float)NN*g5*g5;
  float var = fmaf(sumsq, invN, -mean * mean);
  float scale = gamma[d] * rsqrtf(var + 1e-5f);
  float shift = fmaf(-mean, scale, beta[d]);
  __shared__ float pool[4][128];
  for (int i = t; i < 512; i += 256) ((float*)pool)[i] = 0.f;
  __syncthreads();
  int g0 = batch[n0];
  for (int n = n0 + row; n < n1; n += 2) {
    float4 a = *(const float4*)&ws[WS_ACC + 4 * n];
    float r0 = 1.f / (a.x + 1e-16f);
    float r1 = 1.f / (a.y + 1e-16f);
    float o = g1 * (a.x * r0) + g2 * (a.z * r0)
            + g3 * (a.y * r1) + g4 * (a.w * r1) + g5;
    float v = fmaf(o, scale, shift);
    v = v > 0.f ? v : 0.01f * v;
    int g = batch[n];
    int slot = g - g0;                    // >= 0: batch is sorted
    if (slot < 4) atomicAdd(&pool[slot][d], v);
    else atomicAdd(&out[g * 128 + d], v);
  }
  __syncthreads();
  for (int i = t; i < 512; i += 256) {
    int slot = i >> 7, dd = i & 127;
    int g = g0 + slot;
    float v = pool[slot][dd];
    if (g < NG && v != 0.f) atomicAdd(&out[g * 128 + dd], v);
  }
}

// ==================== fallback path (small ws): direct atomics + BNSUM ====================
extern "C" __global__ __launch_bounds__(256)
void k12f(const int* __restrict__ ei, const float* __restrict__ x,
          const float* __restrict__ eattr,
          const float* __restrict__ Wl, const float* __restrict__ Wr,
          const float* __restrict__ We, const float* __restrict__ bl,
          const float* __restrict__ br, const float* __restrict__ att,
          float* __restrict__ ws)
{
  SMEM_WEIGHTS_DECL
  SMEM_WEIGHTS_LOAD
  int base = (blockIdx.x * 256 + threadIdx.x) * 4;
  if (base >= NE) return;
  SCORE_CORE
  SCORE_LOOPS
  float* acc = ws + WS_ACC;
  float s0, s1;
#define EPI2(xs_, xd_, ae_, accA, accB, dsti)                              \
  { SCORES(xs_, xd_, ae_, accA, accB, s0, s1)                              \
    float e0 = __expf(s0), e1 = __expf(s1);                                \
    float* a = &acc[4 * dsti];                                             \
    atomicAdd(a + 0, e0); atomicAdd(a + 1, e1);                            \
    atomicAdd(a + 2, e0 * xs_); atomicAdd(a + 3, e1 * xs_); }
  EPI2(xs0, xd0, ae0, a00, a10, dd4.x)
  EPI2(xs1, xd1, ae1, a01, a11, dd4.y)
  EPI2(xs2, xd2, ae2, a02, a12, dd4.z)
  EPI2(xs3, xd3, ae3, a03, a13, dd4.w)
#undef EPI2
}

__device__ __forceinline__ float node_out4(float4 a, float wl0, float wl1,
                                           float b0, float b1, float bs)
{
  float r0 = 1.f / (a.x + 1e-16f);
  float r1 = 1.f / (a.y + 1e-16f);
  return 0.5f * (fmaf(wl0, a.z * r0, b0 * (a.x * r0)) +
                 fmaf(wl1, a.w * r1, b1 * (a.y * r1))) + bs;
}

extern "C" __global__ __launch_bounds__(256)
void k3_stats(const float* __restrict__ Wl, const float* __restrict__ bl,
              const float* __restrict__ bias, float* __restrict__ ws)
{
  int d = threadIdx.x & 127;
  int row = threadIdx.x >> 7;
  float wl0 = Wl[d], wl1 = Wl[128 + d];
  float b0 = bl[d], b1 = bl[128 + d];
  float bs = bias[d];
  float sum = 0.f, sq = 0.f;
  for (int n = blockIdx.x * 2 + row; n < NN; n += gridDim.x * 2) {
    float4 a = *(const float4*)&ws[WS_ACC + 4 * n];
    float o = node_out4(a, wl0, wl1, b0, b1, bs);
    sum += o;
    sq = fmaf(o, o, sq);
  }
  __shared__ float l1[256], l2[256];
  l1[threadIdx.x] = sum; l2[threadIdx.x] = sq;
  __syncthreads();
  if (row == 0) {
    atomicAdd(&ws[WS_BNSUM + d], l1[d] + l1[128 + d]);
    atomicAdd(&ws[WS_BNSQ + d], l2[d] + l2[128 + d]);
  }
}

extern "C" __global__ __launch_bounds__(256)
void k4_pool(const int* __restrict__ batch,
             const float* __restrict__ Wl, const float* __restrict__ bl,
             const float* __restrict__ bias, const float* __restrict__ gamma,
             const float* __restrict__ beta,
             float* __restrict__ ws, float* __restrict__ out)
{
  const int CHUNK = (NN + (int)gridDim.x - 1) / (int)gridDim.x;
  int n0 = blockIdx.x * CHUNK;
  if (n0 >= NN) return;
  int n1 = n0 + CHUNK; if (n1 > NN) n1 = NN;
  int d = threadIdx.x & 127;
  int row = threadIdx.x >> 7;
  const float invN = 1.f / (float)NN;
  float mean = ws[WS_BNSUM + d] * invN;
  float var = fmaf(ws[WS_BNSQ + d], invN, -mean * mean);
  float scale = gamma[d] * rsqrtf(var + 1e-5f);
  float shift = fmaf(-mean, scale, beta[d]);
  float wl0 = Wl[d], wl1 = Wl[128 + d];
  float b0 = bl[d], b1 = bl[128 + d];
  float bs = bias[d];
  __shared__ float pool[4][128];
  for (int i = threadIdx.x; i < 512; i += 256) ((float*)pool)[i] = 0.f;
  __syncthreads();
  int g0 = batch[n0];
  for (int n = n0 + row; n < n1; n += 2) {
    float4 a = *(const float4*)&ws[WS_ACC + 4 * n];
    float o = node_out4(a, wl0, wl1, b0, b1, bs);
    float v = fmaf(o, scale, shift);
    v = v > 0.f ? v : 0.01f * v;
    int g = batch[n];
    int slot = g - g0;
    if (slot < 4) atomicAdd(&pool[slot][d], v);
    else atomicAdd(&out[g * 128 + d], v);
  }
  __syncthreads();
  for (int i = threadIdx.x; i < 512; i += 256) {
    int slot = i >> 7, dd = i & 127;
    int g = g0 + slot;
    float v = pool[slot][dd];
    if (g < NG && v != 0.f) atomicAdd(&out[g * 128 + dd], v);
  }
}

extern "C" void kernel_launch(void* const* d_in, const int* in_sizes, int n_in,
                              void* d_out, int out_size, void* d_ws, size_t ws_size,
                              hipStream_t stream) {
  const float* x     = (const float*)d_in[0];
  const int*   ei    = (const int*)d_in[1];
  const float* eattr = (const float*)d_in[2];
  const int*   batch = (const int*)d_in[3];
  const float* Wl    = (const float*)d_in[4];
  const float* bl    = (const float*)d_in[5];
  const float* Wr    = (const float*)d_in[6];
  const float* br    = (const float*)d_in[7];
  const float* We    = (const float*)d_in[8];
  const float* att   = (const float*)d_in[9];
  const float* bias  = (const float*)d_in[10];
  const float* gam   = (const float*)d_in[11];
  const float* bet   = (const float*)d_in[12];
  float* ws  = (float*)d_ws;
  float* out = (float*)d_out;

  const bool dense = (ws_size >= WS_NEED_BYTES);

  hipLaunchKernelGGL(k0_init, dim3(32), dim3(256), 0, stream,
                     ws, att, Wl, Wr, We, bl, br, out, dense ? 1 : 0);
  if (dense) {
    hipLaunchKernelGGL(k_score, dim3(NBLK), dim3(256), 0, stream,
                       ei, x, eattr, Wl, Wr, We, bl, br, att, ws);
    hipLaunchKernelGGL(k_scan1, dim3(256), dim3(256), 0, stream, ws);
    hipLaunchKernelGGL(k_scan2, dim3(1), dim3(256), 0, stream, ws);
    hipLaunchKernelGGL(k_scatter, dim3(NBLK), dim3(256), 0, stream, ws);
    hipLaunchKernelGGL(k_gather, dim3(NBUCK), dim3(256), 0, stream, ws);
    hipLaunchKernelGGL(k4m_pool, dim3(256), dim3(256), 0, stream,
                       batch, Wl, bl, bias, gam, bet, ws, out);
  } else {
    hipLaunchKernelGGL(k12f, dim3((NE / 4 + 255) / 256), dim3(256), 0, stream,
                       ei, x, eattr, Wl, Wr, We, bl, br, att, ws);
    hipLaunchKernelGGL(k3_stats, dim3(256), dim3(256), 0, stream,
                       Wl, bl, bias, ws);
    hipLaunchKernelGGL(k4_pool, dim3(256), dim3(256), 0, stream,
                       batch, Wl, bl, bias, gam, bet, ws, out);
  }
}

// Round 5
// 188.379 us; speedup vs baseline: 2.0633x; 1.0624x over previous
//
#include <hip/hip_runtime.h>
#include <math.h>

#define NN 50000
#define NE 800000
#define NG 64

// ---------------- sort pipeline geometry ----------------
#define CB    2048                        // edges per hist/score block (256 thr x 8)
#define NBLK  391                         // ceil(NE / CB)
#define NBUCK 196                         // ceil(NN / 256), bucket = dst >> 8

static_assert(NBLK * CB >= NE, "chunk cover");
static_assert((NBUCK - 1) == (NN - 1) / 256, "bucket count");
static_assert(NE % 8 == 0, "edge unroll");

// ---------------- ws layout (float offsets) ----------------
#define WS_C     0                       // 8 floats: [h*4 + {att.Wl, att.Wr, att.We, att.B}]
#define WS_ACC   16                      // 4*NN floats: {den0,den1,t10,t11} per node (float4)
#define WS_BNSUM (WS_ACC + 4*NN)         // 128 (fallback path)
#define WS_BNSQ  (WS_BNSUM + 128)        // 128 (fallback path)
#define WS_MOM   WS_BNSUM                // dense path: 14 floats (overlaps BNSUM, paths exclusive)
#define WS_EX    (WS_BNSQ + 128)         // 257 u32 bucket exclusive offsets (pad 272)
#define WS_TOT   (WS_EX + 272)           // 256 u32 bucket totals (scan level 2 input)
#define WS_CNT   (WS_TOT + 256)          // 256*NBLK u32, bucket-major [b][blk]
#define WS_SORT  (WS_CNT + 256*NBLK)     // NE float4 = {e0, e1, xs, asfloat(dst)}, bucket-partitioned
#define WS_END   (WS_SORT + 4*NE)
#define WS_NEED_BYTES ((size_t)WS_END * 4 + 256)

static_assert(((WS_SORT * 4) % 16) == 0, "sort 16B alignment");

// ---------------- shared score machinery ----------------
#define STEP(wl_, wr_, we_, bb_, at_, xs_, xd_, ae_, acc_)                 \
  { float tt = fmaf(we_, ae_, bb_); tt = fmaf(wr_, xd_, tt);               \
    tt = fmaf(wl_, xs_, tt); acc_ = fmaf(fabsf(tt), at_, acc_); }

#define SMEM_WEIGHTS_DECL                                                  \
  __shared__ __align__(16) float sWl[256], sWr[256], sWe[256], sB[256], sAt[256];

#define SMEM_WEIGHTS_LOAD                                                  \
  { int t_ = threadIdx.x;                                                  \
    sWl[t_] = Wl[t_]; sWr[t_] = Wr[t_]; sWe[t_] = We[t_];                  \
    sB[t_] = bl[t_] + br[t_]; sAt[t_] = att[t_]; }                         \
  __syncthreads();

#define SCORES(xs_, xd_, ae_, accA, accB, out0, out1)                      \
  { float lin0 = fmaf(c0.x, xs_, fmaf(c0.y, xd_, fmaf(c0.z, ae_, c0.w))); \
    out0 = fmaf(0.4f, accA, 0.6f * lin0);                                  \
    float lin1 = fmaf(c1.x, xs_, fmaf(c1.y, xd_, fmaf(c1.z, ae_, c1.w))); \
    out1 = fmaf(0.4f, accB, 0.6f * lin1); }

// ---- 4-edge score core (fallback k12f) ----
#define STEP4(c, q0, q1, q2, q3)                                           \
  STEP(wl.c, wr.c, we.c, bb.c, at.c, xs0, xd0, ae0, q0)                    \
  STEP(wl.c, wr.c, we.c, bb.c, at.c, xs1, xd1, ae1, q1)                    \
  STEP(wl.c, wr.c, we.c, bb.c, at.c, xs2, xd2, ae2, q2)                    \
  STEP(wl.c, wr.c, we.c, bb.c, at.c, xs3, xd3, ae3, q3)

#define SCORE_CORE                                                         \
  int4 s4 = *(const int4*)&ei[base];                                       \
  int4 dd4 = *(const int4*)&ei[NE + base];                                 \
  float4 ae4 = *(const float4*)&eattr[base];                               \
  float xs0 = x[s4.x], xs1 = x[s4.y], xs2 = x[s4.z], xs3 = x[s4.w];        \
  float xd0 = x[dd4.x], xd1 = x[dd4.y], xd2 = x[dd4.z], xd3 = x[dd4.w];    \
  float ae0 = ae4.x, ae1 = ae4.y, ae2 = ae4.z, ae3 = ae4.w;

#define SCORE_LOOPS                                                        \
  float a00 = 0.f, a01 = 0.f, a02 = 0.f, a03 = 0.f;                        \
  float a10 = 0.f, a11 = 0.f, a12 = 0.f, a13 = 0.f;                        \
  _Pragma("unroll 2")                                                      \
  for (int j = 0; j < 128; j += 4) {                                       \
    float4 wl = *(const float4*)&sWl[j];                                   \
    float4 wr = *(const float4*)&sWr[j];                                   \
    float4 we = *(const float4*)&sWe[j];                                   \
    float4 bb = *(const float4*)&sB[j];                                    \
    float4 at = *(const float4*)&sAt[j];                                   \
    STEP4(x, a00, a01, a02, a03)                                           \
    STEP4(y, a00, a01, a02, a03)                                           \
    STEP4(z, a00, a01, a02, a03)                                           \
    STEP4(w, a00, a01, a02, a03)                                           \
  }                                                                        \
  _Pragma("unroll 2")                                                      \
  for (int j = 128; j < 256; j += 4) {                                     \
    float4 wl = *(const float4*)&sWl[j];                                   \
    float4 wr = *(const float4*)&sWr[j];                                   \
    float4 we = *(const float4*)&sWe[j];                                   \
    float4 bb = *(const float4*)&sB[j];                                    \
    float4 at = *(const float4*)&sAt[j];                                   \
    STEP4(x, a10, a11, a12, a13)                                           \
    STEP4(y, a10, a11, a12, a13)                                           \
    STEP4(z, a10, a11, a12, a13)                                           \
    STEP4(w, a10, a11, a12, a13)                                           \
  }                                                                        \
  float4 c0 = *(const float4*)&ws[WS_C];                                   \
  float4 c1 = *(const float4*)&ws[WS_C + 4];

// ---- 8-edge variant (dense k_score): one ds_read_b128 set feeds 8 edges.
// Round-4 post-mortem: at EPT=4 the score loop was DS-pipe-bound
// (12.2 waves/CU x 320 b128 x 12cyc ~ 19.5us > 10.4us FMA floor).
// EPT=8 halves wave count -> DS ~9.8us < FMA floor.
#define STEP8(c, Q)                                                        \
  STEP(wl.c, wr.c, we.c, bb.c, at.c, xs0, xd0, ae0, Q##0)                  \
  STEP(wl.c, wr.c, we.c, bb.c, at.c, xs1, xd1, ae1, Q##1)                  \
  STEP(wl.c, wr.c, we.c, bb.c, at.c, xs2, xd2, ae2, Q##2)                  \
  STEP(wl.c, wr.c, we.c, bb.c, at.c, xs3, xd3, ae3, Q##3)                  \
  STEP(wl.c, wr.c, we.c, bb.c, at.c, xs4, xd4, ae4, Q##4)                  \
  STEP(wl.c, wr.c, we.c, bb.c, at.c, xs5, xd5, ae5, Q##5)                  \
  STEP(wl.c, wr.c, we.c, bb.c, at.c, xs6, xd6, ae6, Q##6)                  \
  STEP(wl.c, wr.c, we.c, bb.c, at.c, xs7, xd7, ae7, Q##7)

// ---------------- k_hist: dst histogram per block + all init work ----------------
// Reads ONLY the dst half of ei (3.2MB). Absorbs k0_init (out/MOM zero,
// WS_C attention-dot constants). Block layout MUST match k_score (CB edges).
extern "C" __global__ __launch_bounds__(256)
void k_hist(const int* __restrict__ ei,
            const float* __restrict__ att, const float* __restrict__ Wl,
            const float* __restrict__ Wr, const float* __restrict__ We,
            const float* __restrict__ bl, const float* __restrict__ br,
            float* __restrict__ ws, float* __restrict__ out)
{
  __shared__ unsigned cnt[256];
  cnt[threadIdx.x] = 0u;
  __syncthreads();
  int base = blockIdx.x * CB + (int)threadIdx.x * 8;
  if (base < NE) {
    int4 a = *(const int4*)&ei[NE + base];
    int4 b = *(const int4*)&ei[NE + base + 4];
    atomicAdd(&cnt[((unsigned)a.x) >> 8], 1u);
    atomicAdd(&cnt[((unsigned)a.y) >> 8], 1u);
    atomicAdd(&cnt[((unsigned)a.z) >> 8], 1u);
    atomicAdd(&cnt[((unsigned)a.w) >> 8], 1u);
    atomicAdd(&cnt[((unsigned)b.x) >> 8], 1u);
    atomicAdd(&cnt[((unsigned)b.y) >> 8], 1u);
    atomicAdd(&cnt[((unsigned)b.z) >> 8], 1u);
    atomicAdd(&cnt[((unsigned)b.w) >> 8], 1u);
  }
  __syncthreads();
  unsigned* counts = (unsigned*)(ws + WS_CNT);   // bucket-major [256][NBLK]
  counts[(size_t)threadIdx.x * NBLK + blockIdx.x] = cnt[threadIdx.x];
  // ---- init side-duties ----
  int gid = blockIdx.x * 256 + (int)threadIdx.x;
  if (gid < NG * 128) out[gid] = 0.f;
  if (gid < 14) ws[WS_MOM + gid] = 0.f;
  if (blockIdx.x == 0) {
    __shared__ float red[4][256];
    int t = threadIdx.x;                    // t = h*128 + d
    float a = att[t];
    red[0][t] = a * Wl[t];
    red[1][t] = a * Wr[t];
    red[2][t] = a * We[t];
    red[3][t] = a * (bl[t] + br[t]);
    __syncthreads();
    if (t < 8) {
      int k = t >> 1, h = t & 1;
      float s = 0.f;
      for (int d = 0; d < 128; ++d) s += red[k][h * 128 + d];
      ws[WS_C + h * 4 + k] = s;
    }
  }
}

// ---------------- k_scan1: per-bucket row scan (256 blocks, coalesced) ----------------
extern "C" __global__ __launch_bounds__(256)
void k_scan1(float* __restrict__ ws)
{
  int b = blockIdx.x;
  int t = threadIdx.x;
  unsigned* row = (unsigned*)(ws + WS_CNT) + (size_t)b * NBLK;
  __shared__ unsigned sc[256];
  unsigned carry = 0;
  for (int c = 0; c < NBLK; c += 256) {
    int k = c + t;
    unsigned v = (k < NBLK) ? row[k] : 0u;
    sc[t] = v;
    __syncthreads();
    for (int o = 1; o < 256; o <<= 1) {
      unsigned u = (t >= o) ? sc[t - o] : 0u;
      __syncthreads();
      sc[t] += u;
      __syncthreads();
    }
    unsigned incl = sc[t];
    if (k < NBLK) row[k] = carry + incl - v;   // exclusive within bucket
    unsigned total = sc[255];
    __syncthreads();                            // before sc reuse
    carry += total;
  }
  if (t == 0) ((unsigned*)(ws + WS_TOT))[b] = carry;
}

// ---------------- k_scan2: bucket bases from totals (tiny) ----------------
extern "C" __global__ __launch_bounds__(256)
void k_scan2(float* __restrict__ ws)
{
  int b = threadIdx.x;
  unsigned v = ((const unsigned*)(ws + WS_TOT))[b];
  __shared__ unsigned sc[256];
  sc[b] = v;
  __syncthreads();
  for (int o = 1; o < 256; o <<= 1) {
    unsigned u = (b >= o) ? sc[b - o] : 0u;
    __syncthreads();
    sc[b] += u;
    __syncthreads();
  }
  unsigned* ex = (unsigned*)(ws + WS_EX);
  ex[b] = sc[b] - v;                      // exclusive prefix
  if (b == 255) ex[256] = sc[b];          // == NE
}

// ---------------- k_score: fused score+exp + DIRECT scatter to sorted position ----------------
// 8 edges/thread, zero global atomics in the hot loop. Writes each record
// straight into its bucket region: p = ex[b] + counts[b][blk] + LDS-rank.
// This eliminates the separate k_scatter pass (saves rec0 12.8MB write +
// 12.8MB read + one launch).
extern "C" __global__ __launch_bounds__(256, 2)
void k_score(const int* __restrict__ ei, const float* __restrict__ x,
             const float* __restrict__ eattr,
             const float* __restrict__ Wl, const float* __restrict__ Wr,
             const float* __restrict__ We, const float* __restrict__ bl,
             const float* __restrict__ br, const float* __restrict__ att,
             float* __restrict__ ws)
{
  SMEM_WEIGHTS_DECL
  __shared__ unsigned soff[256];
  { int t_ = threadIdx.x;
    sWl[t_] = Wl[t_]; sWr[t_] = Wr[t_]; sWe[t_] = We[t_];
    sB[t_] = bl[t_] + br[t_]; sAt[t_] = att[t_];
    const unsigned* counts = (const unsigned*)(ws + WS_CNT);
    const unsigned* ex = (const unsigned*)(ws + WS_EX);
    soff[t_] = ex[t_] + counts[(size_t)t_ * NBLK + blockIdx.x];
  }
  __syncthreads();
  int base = blockIdx.x * CB + (int)threadIdx.x * 8;
  if (base >= NE) return;                 // soff already initialized
  int4 sa = *(const int4*)&ei[base];
  int4 sb = *(const int4*)&ei[base + 4];
  int4 da = *(const int4*)&ei[NE + base];
  int4 db = *(const int4*)&ei[NE + base + 4];
  float4 aea = *(const float4*)&eattr[base];
  float4 aeb = *(const float4*)&eattr[base + 4];
  float ae0 = aea.x, ae1 = aea.y, ae2 = aea.z, ae3 = aea.w;
  float ae4 = aeb.x, ae5 = aeb.y, ae6 = aeb.z, ae7 = aeb.w;
  float xs0 = x[sa.x], xs1 = x[sa.y], xs2 = x[sa.z], xs3 = x[sa.w];
  float xs4 = x[sb.x], xs5 = x[sb.y], xs6 = x[sb.z], xs7 = x[sb.w];
  float xd0 = x[da.x], xd1 = x[da.y], xd2 = x[da.z], xd3 = x[da.w];
  float xd4 = x[db.x], xd5 = x[db.y], xd6 = x[db.z], xd7 = x[db.w];
  float q0 = 0.f, q1 = 0.f, q2 = 0.f, q3 = 0.f;
  float q4 = 0.f, q5 = 0.f, q6 = 0.f, q7 = 0.f;
  float r0 = 0.f, r1 = 0.f, r2 = 0.f, r3 = 0.f;
  float r4 = 0.f, r5 = 0.f, r6 = 0.f, r7 = 0.f;
#pragma unroll 2
  for (int j = 0; j < 128; j += 4) {
    float4 wl = *(const float4*)&sWl[j];
    float4 wr = *(const float4*)&sWr[j];
    float4 we = *(const float4*)&sWe[j];
    float4 bb = *(const float4*)&sB[j];
    float4 at = *(const float4*)&sAt[j];
    STEP8(x, q) STEP8(y, q) STEP8(z, q) STEP8(w, q)
  }
#pragma unroll 2
  for (int j = 128; j < 256; j += 4) {
    float4 wl = *(const float4*)&sWl[j];
    float4 wr = *(const float4*)&sWr[j];
    float4 we = *(const float4*)&sWe[j];
    float4 bb = *(const float4*)&sB[j];
    float4 at = *(const float4*)&sAt[j];
    STEP8(x, r) STEP8(y, r) STEP8(z, r) STEP8(w, r)
  }
  float4 c0 = *(const float4*)&ws[WS_C];
  float4 c1 = *(const float4*)&ws[WS_C + 4];
  float4* srt = (float4*)(ws + WS_SORT);
  float s0, s1;
#define EPI(i, dv)                                                         \
  { SCORES(xs##i, xd##i, ae##i, q##i, r##i, s0, s1)                        \
    unsigned d_ = (unsigned)(dv);                                          \
    unsigned p_ = atomicAdd(&soff[d_ >> 8], 1u);                           \
    srt[p_] = make_float4(__expf(s0), __expf(s1), xs##i, __uint_as_float(d_)); }
  EPI(0, da.x) EPI(1, da.y) EPI(2, da.z) EPI(3, da.w)
  EPI(4, db.x) EPI(5, db.y) EPI(6, db.z) EPI(7, db.w)
#undef EPI
}

// ---------------- k_gather: per-bucket coalesced reduce + BN moments ----------------
extern "C" __global__ __launch_bounds__(256)
void k_gather(float* __restrict__ ws)
{
  int b = blockIdx.x;
  const int t = threadIdx.x;
  __shared__ float acc[1024];
  acc[t] = 0.f; acc[256 + t] = 0.f; acc[512 + t] = 0.f; acc[768 + t] = 0.f;
  __syncthreads();
  const unsigned* ex = (const unsigned*)(ws + WS_EX);
  int lo = (int)ex[b], hi = (int)ex[b + 1];
  const float4* srt = (const float4*)(ws + WS_SORT);
  for (int i = lo + t; i < hi; i += 256) {
    float4 r = srt[i];
    int l4 = (int)(__float_as_uint(r.w) & 255u) * 4;
    atomicAdd(&acc[l4 + 0], r.x);
    atomicAdd(&acc[l4 + 1], r.y);
    atomicAdd(&acc[l4 + 2], r.x * r.z);
    atomicAdd(&acc[l4 + 3], r.y * r.z);
  }
  __syncthreads();
  int n = (b << 8) + t;
  float f1 = 0.f, f2 = 0.f, f3 = 0.f, f4 = 0.f;
  if (n < NN) {
    float4 A = make_float4(acc[t * 4], acc[t * 4 + 1], acc[t * 4 + 2], acc[t * 4 + 3]);
    *(float4*)&ws[WS_ACC + 4 * n] = A;
    float r0 = 1.f / (A.x + 1e-16f);
    float r1 = 1.f / (A.y + 1e-16f);
    f1 = A.x * r0; f2 = A.z * r0; f3 = A.y * r1; f4 = A.w * r1;
  }
  // moments: S1..S4, M11,M12,M13,M14,M22,M23,M24,M33,M34,M44
  float pm[14] = { f1, f2, f3, f4,
                   f1*f1, f1*f2, f1*f3, f1*f4,
                   f2*f2, f2*f3, f2*f4,
                   f3*f3, f3*f4, f4*f4 };
#pragma unroll
  for (int k = 0; k < 14; ++k) {
    float v = pm[k];
#pragma unroll
    for (int m = 32; m >= 1; m >>= 1) v += __shfl_xor(v, m);
    pm[k] = v;
  }
  __shared__ float smom[56];
  int wid = t >> 6, lane = t & 63;
  if (lane == 0) {
#pragma unroll
    for (int k = 0; k < 14; ++k) smom[wid * 14 + k] = pm[k];
  }
  __syncthreads();
  if (t < 14) {
    float s = smom[t] + smom[14 + t] + smom[28 + t] + smom[42 + t];
    atomicAdd(&ws[WS_MOM + t], s);
  }
}

// ---------------- k4m: BN from moments + leaky_relu + graph pooling ----------------
extern "C" __global__ __launch_bounds__(256)
void k4m_pool(const int* __restrict__ batch,
              const float* __restrict__ Wl, const float* __restrict__ bl,
              const float* __restrict__ bias, const float* __restrict__ gamma,
              const float* __restrict__ beta,
              float* __restrict__ ws, float* __restrict__ out)
{
  const int CHUNK = (NN + (int)gridDim.x - 1) / (int)gridDim.x;
  int n0 = blockIdx.x * CHUNK;
  if (n0 >= NN) return;
  int n1 = n0 + CHUNK; if (n1 > NN) n1 = NN;
  int t = threadIdx.x;
  int d = t & 127;
  int row = t >> 7;
  float S1 = ws[WS_MOM + 0], S2 = ws[WS_MOM + 1];
  float S3 = ws[WS_MOM + 2], S4 = ws[WS_MOM + 3];
  float M11 = ws[WS_MOM + 4], M12 = ws[WS_MOM + 5], M13 = ws[WS_MOM + 6];
  float M14 = ws[WS_MOM + 7], M22 = ws[WS_MOM + 8], M23 = ws[WS_MOM + 9];
  float M24 = ws[WS_MOM + 10], M33 = ws[WS_MOM + 11], M34 = ws[WS_MOM + 12];
  float M44 = ws[WS_MOM + 13];
  float g1 = 0.5f * bl[d], g2 = 0.5f * Wl[d];
  float g3 = 0.5f * bl[128 + d], g4 = 0.5f * Wl[128 + d];
  float g5 = bias[d];
  const float invN = 1.f / (float)NN;
  float dotS = g1 * S1 + g2 * S2 + g3 * S3 + g4 * S4;
  float mean = (dotS + (float)NN * g5) * invN;
  float sumsq = g1*g1*M11 + g2*g2*M22 + g3*g3*M33 + g4*g4*M44
              + 2.f*(g1*g2*M12 + g1*g3*M13 + g1*g4*M14
                   + g2*g3*M23 + g2*g4*M24 + g3*g4*M34)
              + 2.f*g5*dotS + (float)NN*g5*g5;
  float var = fmaf(sumsq, invN, -mean * mean);
  float scale = gamma[d] * rsqrtf(var + 1e-5f);
  float shift = fmaf(-mean, scale, beta[d]);
  __shared__ float pool[4][128];
  for (int i = t; i < 512; i += 256) ((float*)pool)[i] = 0.f;
  __syncthreads();
  int g0 = batch[n0];
  for (int n = n0 + row; n < n1; n += 2) {
    float4 a = *(const float4*)&ws[WS_ACC + 4 * n];
    float r0 = 1.f / (a.x + 1e-16f);
    float r1 = 1.f / (a.y + 1e-16f);
    float o = g1 * (a.x * r0) + g2 * (a.z * r0)
            + g3 * (a.y * r1) + g4 * (a.w * r1) + g5;
    float v = fmaf(o, scale, shift);
    v = v > 0.f ? v : 0.01f * v;
    int g = batch[n];
    int slot = g - g0;                    // >= 0: batch is sorted
    if (slot < 4) atomicAdd(&pool[slot][d], v);
    else atomicAdd(&out[g * 128 + d], v);
  }
  __syncthreads();
  for (int i = t; i < 512; i += 256) {
    int slot = i >> 7, dd = i & 127;
    int g = g0 + slot;
    float v = pool[slot][dd];
    if (g < NG && v != 0.f) atomicAdd(&out[g * 128 + dd], v);
  }
}

// ==================== fallback path (small ws): direct atomics + BNSUM ====================
extern "C" __global__ __launch_bounds__(256)
void k0_init(float* __restrict__ ws,
             const float* __restrict__ att, const float* __restrict__ Wl,
             const float* __restrict__ Wr, const float* __restrict__ We,
             const float* __restrict__ bl, const float* __restrict__ br,
             float* __restrict__ out)
{
  int tid = blockIdx.x * 256 + threadIdx.x;
  int nt = gridDim.x * 256;
  for (int i = tid; i < 4 * NN; i += nt) ws[WS_ACC + i] = 0.f;
  for (int i = tid; i < 256; i += nt) ws[WS_BNSUM + i] = 0.f;
  for (int i = tid; i < NG * 128; i += nt) out[i] = 0.f;
  if (blockIdx.x == 0) {
    __shared__ float red[4][256];
    int t = threadIdx.x;                    // t = h*128 + d
    float a = att[t];
    red[0][t] = a * Wl[t];
    red[1][t] = a * Wr[t];
    red[2][t] = a * We[t];
    red[3][t] = a * (bl[t] + br[t]);
    __syncthreads();
    if (t < 8) {
      int k = t >> 1, h = t & 1;
      float s = 0.f;
      for (int d = 0; d < 128; ++d) s += red[k][h * 128 + d];
      ws[WS_C + h * 4 + k] = s;
    }
  }
}

extern "C" __global__ __launch_bounds__(256)
void k12f(const int* __restrict__ ei, const float* __restrict__ x,
          const float* __restrict__ eattr,
          const float* __restrict__ Wl, const float* __restrict__ Wr,
          const float* __restrict__ We, const float* __restrict__ bl,
          const float* __restrict__ br, const float* __restrict__ att,
          float* __restrict__ ws)
{
  SMEM_WEIGHTS_DECL
  SMEM_WEIGHTS_LOAD
  int base = (blockIdx.x * 256 + threadIdx.x) * 4;
  if (base >= NE) return;
  SCORE_CORE
  SCORE_LOOPS
  float* acc = ws + WS_ACC;
  float s0, s1;
#define EPI2(xs_, xd_, ae_, accA, accB, dsti)                              \
  { SCORES(xs_, xd_, ae_, accA, accB, s0, s1)                              \
    float e0 = __expf(s0), e1 = __expf(s1);                                \
    float* a = &acc[4 * dsti];                                             \
    atomicAdd(a + 0, e0); atomicAdd(a + 1, e1);                            \
    atomicAdd(a + 2, e0 * xs_); atomicAdd(a + 3, e1 * xs_); }
  EPI2(xs0, xd0, ae0, a00, a10, dd4.x)
  EPI2(xs1, xd1, ae1, a01, a11, dd4.y)
  EPI2(xs2, xd2, ae2, a02, a12, dd4.z)
  EPI2(xs3, xd3, ae3, a03, a13, dd4.w)
#undef EPI2
}

__device__ __forceinline__ float node_out4(float4 a, float wl0, float wl1,
                                           float b0, float b1, float bs)
{
  float r0 = 1.f / (a.x + 1e-16f);
  float r1 = 1.f / (a.y + 1e-16f);
  return 0.5f * (fmaf(wl0, a.z * r0, b0 * (a.x * r0)) +
                 fmaf(wl1, a.w * r1, b1 * (a.y * r1))) + bs;
}

extern "C" __global__ __launch_bounds__(256)
void k3_stats(const float* __restrict__ Wl, const float* __restrict__ bl,
              const float* __restrict__ bias, float* __restrict__ ws)
{
  int d = threadIdx.x & 127;
  int row = threadIdx.x >> 7;
  float wl0 = Wl[d], wl1 = Wl[128 + d];
  float b0 = bl[d], b1 = bl[128 + d];
  float bs = bias[d];
  float sum = 0.f, sq = 0.f;
  for (int n = blockIdx.x * 2 + row; n < NN; n += gridDim.x * 2) {
    float4 a = *(const float4*)&ws[WS_ACC + 4 * n];
    float o = node_out4(a, wl0, wl1, b0, b1, bs);
    sum += o;
    sq = fmaf(o, o, sq);
  }
  __shared__ float l1[256], l2[256];
  l1[threadIdx.x] = sum; l2[threadIdx.x] = sq;
  __syncthreads();
  if (row == 0) {
    atomicAdd(&ws[WS_BNSUM + d], l1[d] + l1[128 + d]);
    atomicAdd(&ws[WS_BNSQ + d], l2[d] + l2[128 + d]);
  }
}

extern "C" __global__ __launch_bounds__(256)
void k4_pool(const int* __restrict__ batch,
             const float* __restrict__ Wl, const float* __restrict__ bl,
             const float* __restrict__ bias, const float* __restrict__ gamma,
             const float* __restrict__ beta,
             float* __restrict__ ws, float* __restrict__ out)
{
  const int CHUNK = (NN + (int)gridDim.x - 1) / (int)gridDim.x;
  int n0 = blockIdx.x * CHUNK;
  if (n0 >= NN) return;
  int n1 = n0 + CHUNK; if (n1 > NN) n1 = NN;
  int d = threadIdx.x & 127;
  int row = threadIdx.x >> 7;
  const float invN = 1.f / (float)NN;
  float mean = ws[WS_BNSUM + d] * invN;
  float var = fmaf(ws[WS_BNSQ + d], invN, -mean * mean);
  float scale = gamma[d] * rsqrtf(var + 1e-5f);
  float shift = fmaf(-mean, scale, beta[d]);
  float wl0 = Wl[d], wl1 = Wl[128 + d];
  float b0 = bl[d], b1 = bl[128 + d];
  float bs = bias[d];
  __shared__ float pool[4][128];
  for (int i = threadIdx.x; i < 512; i += 256) ((float*)pool)[i] = 0.f;
  __syncthreads();
  int g0 = batch[n0];
  for (int n = n0 + row; n < n1; n += 2) {
    float4 a = *(const float4*)&ws[WS_ACC + 4 * n];
    float o = node_out4(a, wl0, wl1, b0, b1, bs);
    float v = fmaf(o, scale, shift);
    v = v > 0.f ? v : 0.01f * v;
    int g = batch[n];
    int slot = g - g0;
    if (slot < 4) atomicAdd(&pool[slot][d], v);
    else atomicAdd(&out[g * 128 + d], v);
  }
  __syncthreads();
  for (int i = threadIdx.x; i < 512; i += 256) {
    int slot = i >> 7, dd = i & 127;
    int g = g0 + slot;
    float v = pool[slot][dd];
    if (g < NG && v != 0.f) atomicAdd(&out[g * 128 + dd], v);
  }
}

extern "C" void kernel_launch(void* const* d_in, const int* in_sizes, int n_in,
                              void* d_out, int out_size, void* d_ws, size_t ws_size,
                              hipStream_t stream) {
  const float* x     = (const float*)d_in[0];
  const int*   ei    = (const int*)d_in[1];
  const float* eattr = (const float*)d_in[2];
  const int*   batch = (const int*)d_in[3];
  const float* Wl    = (const float*)d_in[4];
  const float* bl    = (const float*)d_in[5];
  const float* Wr    = (const float*)d_in[6];
  const float* br    = (const float*)d_in[7];
  const float* We    = (const float*)d_in[8];
  const float* att   = (const float*)d_in[9];
  const float* bias  = (const float*)d_in[10];
  const float* gam   = (const float*)d_in[11];
  const float* bet   = (const float*)d_in[12];
  float* ws  = (float*)d_ws;
  float* out = (float*)d_out;

  const bool dense = (ws_size >= WS_NEED_BYTES);

  if (dense) {
    hipLaunchKernelGGL(k_hist, dim3(NBLK), dim3(256), 0, stream,
                       ei, att, Wl, Wr, We, bl, br, ws, out);
    hipLaunchKernelGGL(k_scan1, dim3(256), dim3(256), 0, stream, ws);
    hipLaunchKernelGGL(k_scan2, dim3(1), dim3(256), 0, stream, ws);
    hipLaunchKernelGGL(k_score, dim3(NBLK), dim3(256), 0, stream,
                       ei, x, eattr, Wl, Wr, We, bl, br, att, ws);
    hipLaunchKernelGGL(k_gather, dim3(NBUCK), dim3(256), 0, stream, ws);
    hipLaunchKernelGGL(k4m_pool, dim3(256), dim3(256), 0, stream,
                       batch, Wl, bl, bias, gam, bet, ws, out);
  } else {
    hipLaunchKernelGGL(k0_init, dim3(128), dim3(256), 0, stream,
                       ws, att, Wl, Wr, We, bl, br, out);
    hipLaunchKernelGGL(k12f, dim3((NE / 4 + 255) / 256), dim3(256), 0, stream,
                       ei, x, eattr, Wl, Wr, We, bl, br, att, ws);
    hipLaunchKernelGGL(k3_stats, dim3(256), dim3(256), 0, stream,
                       Wl, bl, bias, ws);
    hipLaunchKernelGGL(k4_pool, dim3(256), dim3(256), 0, stream,
                       batch, Wl, bl, bias, gam, bet, ws, out);
  }
}